// Round 1
// baseline (758.595 us; speedup 1.0000x reference)
//
#include <hip/hip_runtime.h>

// Problem: N=50000 nodes, D=128, E=625000 edges, 2 node classes, 2 edge classes.
// Outputs concatenated flat in d_out (float32):
//   out0 = x                      [N,128]
//   out1 = concat(x[src],x[dst])  [E,256]
//   out2 = x@Wn + bn              [N,2]
//   out3 = out1@We + be           [E,2]

#define GCN_D 128

// One 32-lane half-wave per node row. Copies x -> out0 and computes node_x.
__global__ void gcn_node_kernel(const float4* __restrict__ x4,
                                const float4* __restrict__ Wn4,  // 128*2 floats = 64 float4
                                const float* __restrict__ bn,
                                float4* __restrict__ out0,
                                float2* __restrict__ out2,
                                int N) {
    int gtid = blockIdx.x * blockDim.x + threadIdx.x;
    int node = gtid >> 5;          // 32 lanes per node
    int l    = gtid & 31;          // float4 index within the 128-float row
    if (node >= N) return;

    float4 v = x4[(size_t)node * 32 + l];
    out0[(size_t)node * 32 + l] = v;

    // Wn is [128,2] row-major; lane l covers k = 4l..4l+3 -> 8 contiguous floats at 8l.
    float4 wa = Wn4[2 * l];        // {Wn[4l][0],Wn[4l][1],Wn[4l+1][0],Wn[4l+1][1]}
    float4 wb = Wn4[2 * l + 1];

    float p0 = v.x * wa.x + v.y * wa.z + v.z * wb.x + v.w * wb.z;
    float p1 = v.x * wa.y + v.y * wa.w + v.z * wb.y + v.w * wb.w;

    // reduce across the 32-lane segment
    for (int m = 16; m >= 1; m >>= 1) {
        p0 += __shfl_xor(p0, m, 32);
        p1 += __shfl_xor(p1, m, 32);
    }
    if (l == 0) {
        out2[node] = make_float2(p0 + bn[0], p1 + bn[1]);
    }
}

// One 64-lane wave per edge. Lanes 0..31 gather x[src], lanes 32..63 gather x[dst].
// Writes the 256-float concatenated row coalesced and fuses edge_x = row @ We + be.
__global__ void gcn_edge_kernel(const float4* __restrict__ x4,
                                const int* __restrict__ eidx,    // [2,E] int32
                                const float4* __restrict__ We4,  // 256*2 floats = 128 float4
                                const float* __restrict__ be,
                                float4* __restrict__ out1,
                                float2* __restrict__ out3,
                                int E) {
    int lane  = threadIdx.x & 63;
    int wave  = (blockIdx.x * blockDim.x + threadIdx.x) >> 6;
    int nwave = (gridDim.x * blockDim.x) >> 6;

    // We is [256,2] row-major; lane covers concat-k = 4*lane..4*lane+3.
    float4 wa = We4[2 * lane];
    float4 wb = We4[2 * lane + 1];
    float b0 = be[0], b1 = be[1];

    int col = lane & 31;

    for (int e = wave; e < E; e += nwave) {
        int row = (lane < 32) ? eidx[e] : eidx[E + e];
        float4 v = x4[(size_t)row * 32 + col];
        out1[(size_t)e * 64 + lane] = v;   // 64 float4 = 256 floats per edge, coalesced

        float p0 = v.x * wa.x + v.y * wa.z + v.z * wb.x + v.w * wb.z;
        float p1 = v.x * wa.y + v.y * wa.w + v.z * wb.y + v.w * wb.w;

        // full 64-lane reduce: src half hits We[0:128], dst half hits We[128:256]
        for (int m = 32; m >= 1; m >>= 1) {
            p0 += __shfl_xor(p0, m);
            p1 += __shfl_xor(p1, m);
        }
        if (lane == 0) {
            out3[e] = make_float2(p0 + b0, p1 + b1);
        }
    }
}

extern "C" void kernel_launch(void* const* d_in, const int* in_sizes, int n_in,
                              void* d_out, int out_size, void* d_ws, size_t ws_size,
                              hipStream_t stream) {
    const float* x   = (const float*)d_in[0];
    const int* eidx  = (const int*)d_in[1];
    const float* Wn  = (const float*)d_in[2];
    const float* bn  = (const float*)d_in[3];
    const float* We  = (const float*)d_in[4];
    const float* be  = (const float*)d_in[5];

    const int N = in_sizes[0] / GCN_D;   // 50000
    const int E = in_sizes[1] / 2;       // 625000

    float* out  = (float*)d_out;
    float* out0 = out;                                   // [N,128]
    float* out1 = out0 + (size_t)N * GCN_D;              // [E,256]
    float* out2 = out1 + (size_t)E * 2 * GCN_D;          // [N,2]
    float* out3 = out2 + (size_t)N * 2;                  // [E,2]

    // Node pass: 32 threads per node.
    {
        int threads = 256;
        int blocks = (N * 32 + threads - 1) / threads;
        gcn_node_kernel<<<blocks, threads, 0, stream>>>(
            (const float4*)x, (const float4*)Wn, bn,
            (float4*)out0, (float2*)out2, N);
    }

    // Edge pass: one wave per edge, grid-stride.
    {
        int threads = 256;
        int blocks = 8192;   // 32768 waves; ~19 edges each
        gcn_edge_kernel<<<blocks, threads, 0, stream>>>(
            (const float4*)x, eidx, (const float4*)We, be,
            (float4*)out1, (float2*)out3, E);
    }
}